// Round 4
// baseline (80.924 us; speedup 1.0000x reference)
//
#include <hip/hip_runtime.h>
#include <stdint.h>

#define N_NODES 3072
#define NPOS 13
#define LL 4096
#define LWORDS 64   // uint64 words per 4096-bit mask row

typedef unsigned long long u64;
typedef unsigned int u32;

// nodeinfo encoding: bits 0-12 = feature bits, bits 13-24 = lane code, bit 31 = valid

// ---------------- K1: per-node lane codes + packed bits + rowneed flags ----------------
__global__ __launch_bounds__(256) void k1_lanes(const float* __restrict__ nf,
                                                u32* __restrict__ nodeinfo,
                                                unsigned char* __restrict__ rowneed) {
    int i = blockIdx.x * 256 + threadIdx.x;      // grid = 12 blocks -> exactly 3072
    const float* b = nf + i * NPOS;
    u32 p = 0; int ln = 0;
#pragma unroll
    for (int k = 0; k < NPOS; ++k) {
        int bit = (int)b[k];                     // values are exactly 0.0 / 1.0
        if (bit) p |= (1u << k);
        if (k < NPOS - 1) ln = ln * 2 + bit;     // MSB-first, first 12 bits
    }
    bool valid = (b[0] >= 0.0f);
    int lv = valid ? ln : 0;
    nodeinfo[i] = ((u32)lv << 13) | p | (valid ? 0x80000000u : 0u);
    rowneed[lv] = 1;                             // benign races, all write 1
}

// ---------------- KA: sign-mask + bit-transpose, skipping unneeded rows ----------
//   T[c][w] bit k  =  (topo[64w+k][c] >= 0)   (restricted to needed lanes)
__global__ __launch_bounds__(256) void kA_mask(const float* __restrict__ topo,
                                               const unsigned char* __restrict__ rowneed,
                                               u64* __restrict__ T) {
    int bid = blockIdx.x;
    int tid = threadIdx.x;
    int tA = bid & 63;   // row tile
    int tB = bid >> 6;   // col tile
    __shared__ float tile[64 * 65];   // pad 65: conflict-free column reads
    __shared__ unsigned char rflag[64], cflag[64];

    if (tid < 16) {
        ((int*)rflag)[tid] = ((const int*)(rowneed + tA * 64))[tid];
        ((int*)cflag)[tid] = ((const int*)(rowneed + tB * 64))[tid];
    }
    __syncthreads();

    const float* src = topo + (size_t)(tA * 64) * LL + tB * 64;
#pragma unroll
    for (int p = 0; p < 4; ++p) {
        int q = p * 1024 + tid * 4;       // linear float index in 64x64 tile
        int r = q >> 6, c = q & 63;
        if (rflag[r]) {
            float4 v = *(const float4*)&src[(size_t)r * LL + c];
            float* d = &tile[r * 65 + c];
            d[0] = v.x; d[1] = v.y; d[2] = v.z; d[3] = v.w;
        }
    }
    __syncthreads();

    int w = tid >> 6, l = tid & 63;
#pragma unroll
    for (int cc = 0; cc < 16; ++cc) {
        int col = w * 16 + cc;            // wave-uniform
        if (!cflag[col]) continue;        // uniform branch: ballot safe
        u64 m = __ballot(tile[l * 65 + col] >= 0.0f);
        if (l == 0) T[(size_t)(tB * 64 + col) * LWORDS + tA] = m;
    }
}

// ---------------- K3: column degrees for 16 targets/block -> dinv ----------------
#define K3I 16
__global__ __launch_bounds__(256) void k3_deg(const u64* __restrict__ T,
                                              const u32* __restrict__ nodeinfo,
                                              float* __restrict__ dinv) {
    __shared__ u64 rows[K3I][LWORDS];     // 8 KB
    __shared__ u32 ninfo[N_NODES];        // 12 KB
    __shared__ int red[K3I][K3I];
    int tid = threadIdx.x;
    int i0 = blockIdx.x * K3I;

    for (int idx = tid; idx < N_NODES / 4; idx += 256)
        ((uint4*)ninfo)[idx] = ((const uint4*)nodeinfo)[idx];
    for (int idx = tid; idx < K3I * LWORDS; idx += 256) {
        int il = idx >> 6, w = idx & 63;
        u32 li = (nodeinfo[i0 + il] >> 13) & 0xFFFu;   // L1/L2-cached re-read
        rows[il][w] = T[(size_t)li * LWORDS + w];
    }
    __syncthreads();

    int il = tid >> 4, ts = tid & 15;     // 16 lanes share one target row
    int i = i0 + il;
    u32 vi = ninfo[i] >> 31;
    int cnt = 0;
    for (int j = ts; j < N_NODES; j += 16) {
        u32 nj = ninfo[j];
        u32 lj = (nj >> 13) & 0xFFFu;
        u32 vj = nj >> 31;
        u32 bit = (u32)(rows[il][lj >> 6] >> (lj & 63)) & 1u;
        cnt += (int)((j == i) | (vi & vj & bit));
    }
    red[il][ts] = cnt;
    __syncthreads();
    if (tid < K3I) {
        int d = 0;
#pragma unroll
        for (int t = 0; t < K3I; ++t) d += red[tid][t];
        dinv[i0 + tid] = (d > 0) ? (1.0f / sqrtf((float)d)) : 0.0f;
    }
}

// ---------------- K4: agg[i][f] += dinv_i * sum_{j in half} adj[j,i]*dinv_j*bit_f(j) ----
#define K4I 16
#define JH (N_NODES / 2)
__global__ __launch_bounds__(256) void k4_agg(const u64* __restrict__ T,
                                              const u32* __restrict__ nodeinfo,
                                              const float* __restrict__ dinv,
                                              float* __restrict__ agg) {
    __shared__ u64 rows[K4I][LWORDS];         // 8 KB
    __shared__ u32 nin2[JH];                  // 6 KB
    __shared__ float dv2[JH];                 // 6 KB
    __shared__ float red[K4I][K4I][NPOS];     // 13 KB
    int tid = threadIdx.x;
    int i0 = blockIdx.x * K4I;
    int jbase = blockIdx.y * JH;

    for (int idx = tid; idx < JH / 4; idx += 256) {
        ((uint4*)nin2)[idx] = ((const uint4*)(nodeinfo + jbase))[idx];
        ((float4*)dv2)[idx] = ((const float4*)(dinv + jbase))[idx];
    }
    for (int idx = tid; idx < K4I * LWORDS; idx += 256) {
        int il = idx >> 6, w = idx & 63;
        u32 li = (nodeinfo[i0 + il] >> 13) & 0xFFFu;
        rows[il][w] = T[(size_t)li * LWORDS + w];
    }
    __syncthreads();

    int il = tid >> 4, ts = tid & 15;
    int i = i0 + il;
    u32 vi = nodeinfo[i] >> 31;
    float acc[NPOS];
#pragma unroll
    for (int f = 0; f < NPOS; ++f) acc[f] = 0.0f;
    for (int jj = ts; jj < JH; jj += 16) {
        int j = jbase + jj;
        u32 nj = nin2[jj];
        u32 lj = (nj >> 13) & 0xFFFu;
        u32 vj = nj >> 31;
        u32 bit = (u32)(rows[il][lj >> 6] >> (lj & 63)) & 1u;
        bool adj = (j == i) | (vi & vj & bit);
        float w = adj ? dv2[jj] : 0.0f;
#pragma unroll
        for (int f = 0; f < NPOS; ++f)
            acc[f] += ((nj >> f) & 1u) ? w : 0.0f;
    }
#pragma unroll
    for (int f = 0; f < NPOS; ++f) red[il][ts][f] = acc[f];
    __syncthreads();
    // finalize: 208 threads, one (il, f) each; exactly 2 atomics/element across grid.y
    if (tid < K4I * NPOS) {
        int fil = tid / NPOS, f = tid - fil * NPOS;
        float s = 0.0f;
#pragma unroll
        for (int t = 0; t < K4I; ++t) s += red[fil][t][f];
        atomicAdd(&agg[(size_t)(i0 + fil) * NPOS + f], dinv[i0 + fil] * s);
    }
}

// ---------------- K5: out[i][n] = bias[n] + sum_f agg[i][f] * W[n][f] ----------------
#define NT 256
#define IT 32
__global__ __launch_bounds__(256) void k5_out(const float* __restrict__ agg,
                                              const float* __restrict__ W,
                                              const float* __restrict__ bias,
                                              float* __restrict__ out) {
    __shared__ float Wt[NT * NPOS];   // 13312 B
    __shared__ float bt[NT];
    __shared__ float at[IT * NPOS];
    int tid = threadIdx.x;
    int n0 = blockIdx.x * NT;
    int i0 = blockIdx.y * IT;
    const float4* Wsrc = (const float4*)&W[(size_t)n0 * NPOS];
    for (int idx = tid; idx < NT * NPOS / 4; idx += 256) ((float4*)Wt)[idx] = Wsrc[idx];
    if (tid < NT / 4) ((float4*)bt)[tid] = ((const float4*)&bias[n0])[tid];
    if (tid < IT * NPOS / 4) ((float4*)at)[tid] = ((const float4*)&agg[(size_t)i0 * NPOS])[tid];
    __syncthreads();

    int n4 = (tid & 63) << 2;        // col group: 0..252
    int r0 = (tid >> 6) << 3;        // row group: 0,8,16,24

    float wr[NPOS][4];
#pragma unroll
    for (int f = 0; f < NPOS; ++f)
#pragma unroll
        for (int r = 0; r < 4; ++r)
            wr[f][r] = Wt[(n4 + r) * NPOS + f];
    float b0 = bt[n4], b1 = bt[n4 + 1], b2 = bt[n4 + 2], b3 = bt[n4 + 3];

#pragma unroll
    for (int q = 0; q < 8; ++q) {
        int il = r0 + q;
        float a0 = b0, a1 = b1, a2 = b2, a3 = b3;
#pragma unroll
        for (int f = 0; f < NPOS; ++f) {
            float av = at[il * NPOS + f];
            a0 += av * wr[f][0];
            a1 += av * wr[f][1];
            a2 += av * wr[f][2];
            a3 += av * wr[f][3];
        }
        float4 o = make_float4(a0, a1, a2, a3);
        *(float4*)&out[(size_t)(i0 + il) * N_NODES + n0 + n4] = o;
    }
}

extern "C" void kernel_launch(void* const* d_in, const int* in_sizes, int n_in,
                              void* d_out, int out_size, void* d_ws, size_t ws_size,
                              hipStream_t stream) {
    const float* nf   = (const float*)d_in[0];   // node_feature [1,3072,13]
    const float* topo = (const float*)d_in[1];   // topo [1,1,4096,4096]
    const float* W    = (const float*)d_in[2];   // gcn_weight [3072,13]
    const float* bias = (const float*)d_in[3];   // gcn_bias [3072]
    float* out = (float*)d_out;

    // ws layout (agg and rowneed contiguous -> single zeroing memset)
    char* ws = (char*)d_ws;
    u32*           nodeinfo = (u32*)ws;                             // 12 KB
    float*         dinv     = (float*)(ws + 12288);                 // 12 KB
    float*         agg      = (float*)(ws + 24576);                 // 159744 B
    unsigned char* rowneed  = (unsigned char*)(ws + 24576 + 159744);// 4 KB
    u64*           T        = (u64*)(ws + 262144);                  // 2 MB [4096][64]

    hipMemsetAsync(ws + 24576, 0, 159744 + 4096, stream);           // zero agg + rowneed
    k1_lanes<<<N_NODES / 256, 256, 0, stream>>>(nf, nodeinfo, rowneed);
    kA_mask<<<(LL / 64) * (LL / 64), 256, 0, stream>>>(topo, rowneed, T);
    k3_deg<<<N_NODES / K3I, 256, 0, stream>>>(T, nodeinfo, dinv);
    dim3 g4(N_NODES / K4I, 2);
    k4_agg<<<g4, 256, 0, stream>>>(T, nodeinfo, dinv, agg);
    dim3 g5(N_NODES / NT, N_NODES / IT);
    k5_out<<<g5, 256, 0, stream>>>(agg, W, bias, out);
}

// Round 5
// 63.130 us; speedup vs baseline: 1.2819x; 1.2819x over previous
//
#include <hip/hip_runtime.h>
#include <stdint.h>

#define N_NODES 3072
#define NPOS 13
#define LL 4096
#define LWORDS 64   // uint64 words per 4096-bit mask row
#define K1B 12      // k1 blocks (partial bitmaps)

typedef unsigned long long u64;
typedef unsigned int u32;

// nodeinfo encoding: bits 0-12 = feature bits, bits 13-24 = lane code, bit 31 = valid

// ---------------- K1: nodeinfo + per-block partial lane bitmaps (no pre-zero needed) ----
__global__ __launch_bounds__(256) void k1_lanes(const float* __restrict__ nf,
                                                u32* __restrict__ nodeinfo,
                                                u64* __restrict__ rowmask) {
    __shared__ u64 bm[LWORDS];
    int tid = threadIdx.x;
    int bid = blockIdx.x;
    if (tid < LWORDS) bm[tid] = 0;
    __syncthreads();
    int i = bid * 256 + tid;                     // grid = 12 blocks -> exactly 3072
    const float* b = nf + i * NPOS;
    u32 p = 0; int ln = 0;
#pragma unroll
    for (int k = 0; k < NPOS; ++k) {
        int bit = (int)b[k];                     // values are exactly 0.0 / 1.0
        if (bit) p |= (1u << k);
        if (k < NPOS - 1) ln = ln * 2 + bit;     // MSB-first, first 12 bits
    }
    bool valid = (b[0] >= 0.0f);
    int lv = valid ? ln : 0;
    nodeinfo[i] = ((u32)lv << 13) | p | (valid ? 0x80000000u : 0u);
    atomicOr(&bm[lv >> 6], 1ull << (lv & 63));
    __syncthreads();
    if (tid < LWORDS) rowmask[bid * LWORDS + tid] = bm[tid];   // full overwrite of own slice
}

// ---------------- KA: sign-mask + bit-transpose, skipping unneeded rows ----------
//   T[c][w] bit k  =  (topo[64w+k][c] >= 0)   (restricted to needed lanes)
__global__ __launch_bounds__(256) void kA_mask(const float* __restrict__ topo,
                                               const u64* __restrict__ rowmask,
                                               u64* __restrict__ T) {
    int bid = blockIdx.x;
    int tid = threadIdx.x;
    int tA = bid & 63;   // row tile
    int tB = bid >> 6;   // col tile
    __shared__ float tile[64 * 65];   // pad 65: conflict-free column reads
    __shared__ u64 flags[2];          // [0]=row bits (word tA), [1]=col bits (word tB)

    if (tid < 2) {
        int sel = tid ? tB : tA;
        u64 m = 0;
#pragma unroll
        for (int b = 0; b < K1B; ++b) m |= rowmask[b * LWORDS + sel];
        flags[tid] = m;
    }
    __syncthreads();
    u64 rbits = flags[0], cbits = flags[1];

    const float* src = topo + (size_t)(tA * 64) * LL + tB * 64;
#pragma unroll
    for (int p = 0; p < 4; ++p) {
        int q = p * 1024 + tid * 4;       // linear float index in 64x64 tile
        int r = q >> 6, c = q & 63;
        if ((rbits >> r) & 1) {
            float4 v = *(const float4*)&src[(size_t)r * LL + c];
            float* d = &tile[r * 65 + c];
            d[0] = v.x; d[1] = v.y; d[2] = v.z; d[3] = v.w;
        }
    }
    __syncthreads();

    int w = tid >> 6, l = tid & 63;
#pragma unroll
    for (int cc = 0; cc < 16; ++cc) {
        int col = w * 16 + cc;            // wave-uniform
        if (!((cbits >> col) & 1)) continue;   // uniform branch: ballot safe
        u64 m = __ballot(tile[l * 65 + col] >= 0.0f);
        if (l == 0) T[(size_t)(tB * 64 + col) * LWORDS + tA] = m;
    }
}

// ---------------- K3: column degree -> dinv[i] = 1/sqrt(deg) ----------------
__global__ __launch_bounds__(256) void k3_deg(const u64* __restrict__ T,
                                              const u32* __restrict__ nodeinfo,
                                              float* __restrict__ dinv) {
    int i = blockIdx.x;
    __shared__ u64 row[LWORDS];
    __shared__ int red[4];
    int tid = threadIdx.x;
    u32 ni = nodeinfo[i];
    u32 li = (ni >> 13) & 0xFFFu;
    u32 vi = ni >> 31;
    if (tid < LWORDS) row[tid] = T[(size_t)li * LWORDS + tid];
    __syncthreads();
    int cnt = 0;
    for (int j = tid; j < N_NODES; j += 256) {
        u32 nj = nodeinfo[j];                    // L1-resident (12 KB)
        u32 lj = (nj >> 13) & 0xFFFu;
        u32 vj = nj >> 31;
        u32 bit = (u32)(row[lj >> 6] >> (lj & 63)) & 1u;
        cnt += (int)((j == i) | (vi & vj & bit));
    }
#pragma unroll
    for (int off = 32; off; off >>= 1) cnt += __shfl_down(cnt, off);
    if ((tid & 63) == 0) red[tid >> 6] = cnt;
    __syncthreads();
    if (tid == 0) {
        int d = red[0] + red[1] + red[2] + red[3];
        dinv[i] = (d > 0) ? (1.0f / sqrtf((float)d)) : 0.0f;
    }
}

// ---------------- K4: agg[i][f] = dinv_i * sum_j adj[j,i]*dinv_j*bit_f(j) ----------------
__global__ __launch_bounds__(256) void k4_agg(const u64* __restrict__ T,
                                              const u32* __restrict__ nodeinfo,
                                              const float* __restrict__ dinv,
                                              float* __restrict__ agg) {
    int i = blockIdx.x;
    __shared__ u64 row[LWORDS];
    __shared__ float red[4][NPOS];
    int tid = threadIdx.x;
    u32 ni = nodeinfo[i];
    u32 li = (ni >> 13) & 0xFFFu;
    u32 vi = ni >> 31;
    if (tid < LWORDS) row[tid] = T[(size_t)li * LWORDS + tid];
    __syncthreads();
    float acc[NPOS];
#pragma unroll
    for (int f = 0; f < NPOS; ++f) acc[f] = 0.0f;
    for (int j = tid; j < N_NODES; j += 256) {
        u32 nj = nodeinfo[j];                    // L1-resident
        u32 lj = (nj >> 13) & 0xFFFu;
        u32 vj = nj >> 31;
        u32 bit = (u32)(row[lj >> 6] >> (lj & 63)) & 1u;
        bool adj = (j == i) | (vi & vj & bit);
        float w = adj ? dinv[j] : 0.0f;          // L1-resident
#pragma unroll
        for (int f = 0; f < NPOS; ++f)
            acc[f] += ((nj >> f) & 1u) ? w : 0.0f;
    }
    int l = tid & 63, wv = tid >> 6;
#pragma unroll
    for (int f = 0; f < NPOS; ++f) {
        float v = acc[f];
#pragma unroll
        for (int off = 32; off; off >>= 1) v += __shfl_down(v, off);
        if (l == 0) red[wv][f] = v;
    }
    __syncthreads();
    if (tid < NPOS) {                            // full overwrite: no pre-zero needed
        float di = dinv[i];
        agg[i * NPOS + tid] = di * (red[0][tid] + red[1][tid] + red[2][tid] + red[3][tid]);
    }
}

// ---------------- K5: out[i][n] = bias[n] + sum_f agg[i][f] * W[n][f] ----------------
#define NT 256
#define IT 32
__global__ __launch_bounds__(256) void k5_out(const float* __restrict__ agg,
                                              const float* __restrict__ W,
                                              const float* __restrict__ bias,
                                              float* __restrict__ out) {
    __shared__ float Wt[NT * NPOS];   // 13312 B
    __shared__ float bt[NT];
    __shared__ float at[IT * NPOS];
    int tid = threadIdx.x;
    int n0 = blockIdx.x * NT;
    int i0 = blockIdx.y * IT;
    const float4* Wsrc = (const float4*)&W[(size_t)n0 * NPOS];
    for (int idx = tid; idx < NT * NPOS / 4; idx += 256) ((float4*)Wt)[idx] = Wsrc[idx];
    if (tid < NT / 4) ((float4*)bt)[tid] = ((const float4*)&bias[n0])[tid];
    if (tid < IT * NPOS / 4) ((float4*)at)[tid] = ((const float4*)&agg[(size_t)i0 * NPOS])[tid];
    __syncthreads();

    int n4 = (tid & 63) << 2;        // col group: 0..252
    int r0 = (tid >> 6) << 3;        // row group: 0,8,16,24

    float wr[NPOS][4];
#pragma unroll
    for (int f = 0; f < NPOS; ++f)
#pragma unroll
        for (int r = 0; r < 4; ++r)
            wr[f][r] = Wt[(n4 + r) * NPOS + f];
    float b0 = bt[n4], b1 = bt[n4 + 1], b2 = bt[n4 + 2], b3 = bt[n4 + 3];

#pragma unroll
    for (int q = 0; q < 8; ++q) {
        int il = r0 + q;
        float a0 = b0, a1 = b1, a2 = b2, a3 = b3;
#pragma unroll
        for (int f = 0; f < NPOS; ++f) {
            float av = at[il * NPOS + f];
            a0 += av * wr[f][0];
            a1 += av * wr[f][1];
            a2 += av * wr[f][2];
            a3 += av * wr[f][3];
        }
        float4 o = make_float4(a0, a1, a2, a3);
        *(float4*)&out[(size_t)(i0 + il) * N_NODES + n0 + n4] = o;
    }
}

extern "C" void kernel_launch(void* const* d_in, const int* in_sizes, int n_in,
                              void* d_out, int out_size, void* d_ws, size_t ws_size,
                              hipStream_t stream) {
    const float* nf   = (const float*)d_in[0];   // node_feature [1,3072,13]
    const float* topo = (const float*)d_in[1];   // topo [1,1,4096,4096]
    const float* W    = (const float*)d_in[2];   // gcn_weight [3072,13]
    const float* bias = (const float*)d_in[3];   // gcn_bias [3072]
    float* out = (float*)d_out;

    // ws layout — every buffer fully overwritten by its producer; no memset anywhere
    char* ws = (char*)d_ws;
    u32*   nodeinfo = (u32*)ws;                          // 12 KB
    float* dinv     = (float*)(ws + 12288);              // 12 KB
    float* agg      = (float*)(ws + 24576);              // 159744 B
    u64*   rowmask  = (u64*)(ws + 24576 + 159744);       // 12 * 512 B
    u64*   T        = (u64*)(ws + 262144);               // 2 MB [4096][64]

    k1_lanes<<<K1B, 256, 0, stream>>>(nf, nodeinfo, rowmask);
    kA_mask<<<(LL / 64) * (LL / 64), 256, 0, stream>>>(topo, rowmask, T);
    k3_deg<<<N_NODES, 256, 0, stream>>>(T, nodeinfo, dinv);
    k4_agg<<<N_NODES, 256, 0, stream>>>(T, nodeinfo, dinv, agg);
    dim3 g5(N_NODES / NT, N_NODES / IT);
    k5_out<<<g5, 256, 0, stream>>>(agg, W, bias, out);
}

// Round 6
// 57.646 us; speedup vs baseline: 1.4038x; 1.0951x over previous
//
#include <hip/hip_runtime.h>
#include <stdint.h>

#define N_NODES 3072
#define NPOS 13
#define LL 4096
#define LWORDS 64   // uint64 words per 4096-bit mask row
#define K1B 12      // k1 blocks (partial bitmaps)

typedef unsigned long long u64;
typedef unsigned int u32;

// nodeinfo encoding: bits 0-12 = feature bits, bits 13-24 = lane code, bit 31 = valid

// ---------------- K1: nodeinfo + per-block partial lane bitmaps (no pre-zero needed) ----
__global__ __launch_bounds__(256) void k1_lanes(const float* __restrict__ nf,
                                                u32* __restrict__ nodeinfo,
                                                u64* __restrict__ rowmask) {
    __shared__ u64 bm[LWORDS];
    int tid = threadIdx.x;
    int bid = blockIdx.x;
    if (tid < LWORDS) bm[tid] = 0;
    __syncthreads();
    int i = bid * 256 + tid;                     // grid = 12 blocks -> exactly 3072
    const float* b = nf + i * NPOS;
    u32 p = 0; int ln = 0;
#pragma unroll
    for (int k = 0; k < NPOS; ++k) {
        int bit = (int)b[k];                     // values are exactly 0.0 / 1.0
        if (bit) p |= (1u << k);
        if (k < NPOS - 1) ln = ln * 2 + bit;     // MSB-first, first 12 bits
    }
    bool valid = (b[0] >= 0.0f);
    int lv = valid ? ln : 0;
    nodeinfo[i] = ((u32)lv << 13) | p | (valid ? 0x80000000u : 0u);
    atomicOr(&bm[lv >> 6], 1ull << (lv & 63));
    __syncthreads();
    if (tid < LWORDS) rowmask[bid * LWORDS + tid] = bm[tid];   // full overwrite of own slice
}

// ---------------- KA: sign-mask + bit-transpose, skipping unneeded rows ----------
//   T[c][w] bit k  =  (topo[64w+k][c] >= 0)   (restricted to needed lanes)
__global__ __launch_bounds__(256) void kA_mask(const float* __restrict__ topo,
                                               const u64* __restrict__ rowmask,
                                               u64* __restrict__ T) {
    int bid = blockIdx.x;
    int tid = threadIdx.x;
    int tA = bid & 63;   // row tile
    int tB = bid >> 6;   // col tile
    __shared__ float tile[64 * 65];   // pad 65: conflict-free column reads
    __shared__ u64 flags[2];          // [0]=row bits (word tA), [1]=col bits (word tB)

    if (tid < 2) {
        int sel = tid ? tB : tA;
        u64 m = 0;
#pragma unroll
        for (int b = 0; b < K1B; ++b) m |= rowmask[b * LWORDS + sel];
        flags[tid] = m;
    }
    __syncthreads();
    u64 rbits = flags[0], cbits = flags[1];

    const float* src = topo + (size_t)(tA * 64) * LL + tB * 64;
#pragma unroll
    for (int p = 0; p < 4; ++p) {
        int q = p * 1024 + tid * 4;       // linear float index in 64x64 tile
        int r = q >> 6, c = q & 63;
        if ((rbits >> r) & 1) {
            float4 v = *(const float4*)&src[(size_t)r * LL + c];
            float* d = &tile[r * 65 + c];
            d[0] = v.x; d[1] = v.y; d[2] = v.z; d[3] = v.w;
        }
    }
    __syncthreads();

    int w = tid >> 6, l = tid & 63;
#pragma unroll
    for (int cc = 0; cc < 16; ++cc) {
        int col = w * 16 + cc;            // wave-uniform
        if (!((cbits >> col) & 1)) continue;   // uniform branch: ballot safe
        u64 m = __ballot(tile[l * 65 + col] >= 0.0f);
        if (l == 0) T[(size_t)(tB * 64 + col) * LWORDS + tA] = m;
    }
}

// ---------------- K3: column degree -> dinv[i] = 1/sqrt(deg) ----------------
// Inner loop drops the (j==i) term (exact self-correction at finalize) and
// folds 64 pair-tests per wave into one ballot+popcount.
__global__ __launch_bounds__(256) void k3_deg(const u64* __restrict__ T,
                                              const u32* __restrict__ nodeinfo,
                                              float* __restrict__ dinv) {
    int i = blockIdx.x;
    __shared__ u64 row[LWORDS];
    __shared__ int red[4];
    int tid = threadIdx.x;
    u32 ni = nodeinfo[i];
    u32 li = (ni >> 13) & 0xFFFu;
    u32 vi = ni >> 31;
    if (tid < LWORDS) row[tid] = T[(size_t)li * LWORDS + tid];
    __syncthreads();
    int lane = tid & 63;
    int cnt = 0;
    for (int j = tid; j < N_NODES; j += 256) {   // lanes hold consecutive j: ballot-safe
        u32 nj = nodeinfo[j];                    // L1-resident (12 KB)
        u32 lj = (nj >> 13) & 0xFFFu;
        u32 vj = nj >> 31;
        u32 bit = (u32)(row[lj >> 6] >> (lj & 63)) & 1u;
        u64 m = __ballot(vi & vj & bit);
        if (lane == 0) cnt += __popcll(m);
    }
    if (lane == 0) red[tid >> 6] = cnt;
    __syncthreads();
    if (tid == 0) {
        u32 selfbit = ((u32)(row[li >> 6] >> (li & 63)) & 1u) & vi;
        int d = red[0] + red[1] + red[2] + red[3] + (int)(1u - selfbit);
        dinv[i] = 1.0f / sqrtf((float)d);        // d >= 1 always (self loop)
    }
}

// ---------------- K4: agg[i][f] = dinv_i * sum_j adj[j,i]*dinv_j*bit_f(j) ----------------
// Inner loop drops (j==i) (exact correction at finalize); reduction tail is a
// two-stage LDS transpose instead of 13x 6-step shuffles.
__global__ __launch_bounds__(256) void k4_agg(const u64* __restrict__ T,
                                              const u32* __restrict__ nodeinfo,
                                              const float* __restrict__ dinv,
                                              float* __restrict__ agg) {
    int i = blockIdx.x;
    __shared__ u64 row[LWORDS];
    __shared__ float red[256 * NPOS];     // 13312 B, [tid][f]
    __shared__ float red2[16 * NPOS];     // 832 B,   [grp][f]
    int tid = threadIdx.x;
    u32 ni = nodeinfo[i];
    u32 li = (ni >> 13) & 0xFFFu;
    u32 vi = ni >> 31;
    if (tid < LWORDS) row[tid] = T[(size_t)li * LWORDS + tid];
    __syncthreads();
    float acc[NPOS];
#pragma unroll
    for (int f = 0; f < NPOS; ++f) acc[f] = 0.0f;
    for (int j = tid; j < N_NODES; j += 256) {
        u32 nj = nodeinfo[j];                    // L1-resident
        u32 lj = (nj >> 13) & 0xFFFu;
        u32 vj = nj >> 31;
        u32 bit = (u32)(row[lj >> 6] >> (lj & 63)) & 1u;
        u32 a = vi & vj & bit;                   // self term handled at finalize
        float w = a ? dinv[j] : 0.0f;            // L1-resident
#pragma unroll
        for (int f = 0; f < NPOS; ++f)
            acc[f] += ((nj >> f) & 1u) ? w : 0.0f;
    }
#pragma unroll
    for (int f = 0; f < NPOS; ++f) red[tid * NPOS + f] = acc[f];
    __syncthreads();
    if (tid < 16 * NPOS) {                       // 208 threads: sum 16 entries each
        int g = tid / NPOS, f = tid - g * NPOS;
        float s = 0.0f;
#pragma unroll
        for (int e = 0; e < 16; ++e) s += red[(g * 16 + e) * NPOS + f];
        red2[g * NPOS + f] = s;
    }
    __syncthreads();
    if (tid < NPOS) {
        float s = 0.0f;
#pragma unroll
        for (int g = 0; g < 16; ++g) s += red2[g * NPOS + tid];
        u32 selfbit = ((u32)(row[li >> 6] >> (li & 63)) & 1u) & vi;
        float di = dinv[i];
        float self = (1.0f - (float)selfbit) * di * (float)((ni >> tid) & 1u);
        agg[i * NPOS + tid] = di * (s + self);
    }
}

// ---------------- K5: out[i][n] = bias[n] + sum_f agg[i][f] * W[n][f] ----------------
#define NT 256
#define IT 32
__global__ __launch_bounds__(256) void k5_out(const float* __restrict__ agg,
                                              const float* __restrict__ W,
                                              const float* __restrict__ bias,
                                              float* __restrict__ out) {
    __shared__ float Wt[NT * NPOS];   // 13312 B
    __shared__ float bt[NT];
    __shared__ float at[IT * NPOS];
    int tid = threadIdx.x;
    int n0 = blockIdx.x * NT;
    int i0 = blockIdx.y * IT;
    const float4* Wsrc = (const float4*)&W[(size_t)n0 * NPOS];
    for (int idx = tid; idx < NT * NPOS / 4; idx += 256) ((float4*)Wt)[idx] = Wsrc[idx];
    if (tid < NT / 4) ((float4*)bt)[tid] = ((const float4*)&bias[n0])[tid];
    if (tid < IT * NPOS / 4) ((float4*)at)[tid] = ((const float4*)&agg[(size_t)i0 * NPOS])[tid];
    __syncthreads();

    int n4 = (tid & 63) << 2;        // col group: 0..252
    int r0 = (tid >> 6) << 3;        // row group: 0,8,16,24

    float wr[NPOS][4];
#pragma unroll
    for (int f = 0; f < NPOS; ++f)
#pragma unroll
        for (int r = 0; r < 4; ++r)
            wr[f][r] = Wt[(n4 + r) * NPOS + f];
    float b0 = bt[n4], b1 = bt[n4 + 1], b2 = bt[n4 + 2], b3 = bt[n4 + 3];

#pragma unroll
    for (int q = 0; q < 8; ++q) {
        int il = r0 + q;
        float a0 = b0, a1 = b1, a2 = b2, a3 = b3;
#pragma unroll
        for (int f = 0; f < NPOS; ++f) {
            float av = at[il * NPOS + f];
            a0 += av * wr[f][0];
            a1 += av * wr[f][1];
            a2 += av * wr[f][2];
            a3 += av * wr[f][3];
        }
        float4 o = make_float4(a0, a1, a2, a3);
        *(float4*)&out[(size_t)(i0 + il) * N_NODES + n0 + n4] = o;
    }
}

extern "C" void kernel_launch(void* const* d_in, const int* in_sizes, int n_in,
                              void* d_out, int out_size, void* d_ws, size_t ws_size,
                              hipStream_t stream) {
    const float* nf   = (const float*)d_in[0];   // node_feature [1,3072,13]
    const float* topo = (const float*)d_in[1];   // topo [1,1,4096,4096]
    const float* W    = (const float*)d_in[2];   // gcn_weight [3072,13]
    const float* bias = (const float*)d_in[3];   // gcn_bias [3072]
    float* out = (float*)d_out;

    // ws layout — every buffer fully overwritten by its producer; no memset anywhere
    char* ws = (char*)d_ws;
    u32*   nodeinfo = (u32*)ws;                          // 12 KB
    float* dinv     = (float*)(ws + 12288);              // 12 KB
    float* agg      = (float*)(ws + 24576);              // 159744 B
    u64*   rowmask  = (u64*)(ws + 24576 + 159744);       // 12 * 512 B
    u64*   T        = (u64*)(ws + 262144);               // 2 MB [4096][64]

    k1_lanes<<<K1B, 256, 0, stream>>>(nf, nodeinfo, rowmask);
    kA_mask<<<(LL / 64) * (LL / 64), 256, 0, stream>>>(topo, rowmask, T);
    k3_deg<<<N_NODES, 256, 0, stream>>>(T, nodeinfo, dinv);
    k4_agg<<<N_NODES, 256, 0, stream>>>(T, nodeinfo, dinv, agg);
    dim3 g5(N_NODES / NT, N_NODES / IT);
    k5_out<<<g5, 256, 0, stream>>>(agg, W, bias, out);
}

// Round 7
// 54.941 us; speedup vs baseline: 1.4729x; 1.0492x over previous
//
#include <hip/hip_runtime.h>
#include <stdint.h>

#define N_NODES 3072
#define NPOS 13
#define LL 4096
#define LWORDS 64   // uint64 words per 4096-bit mask row
#define K1B 12      // k1 blocks (partial bitmaps)
#define KS 8        // k4m K-segments
#define CPS 12      // chunks of 32 j per segment (8*12*32 = 3072)

typedef unsigned long long u64;
typedef unsigned int u32;
typedef __attribute__((ext_vector_type(4))) float f32x4;
typedef __attribute__((ext_vector_type(8))) short bf16x8;

// nodeinfo encoding: bits 0-12 = feature bits, bits 13-24 = lane code, bit 31 = valid

// ---------------- K1: nodeinfo + per-block partial lane bitmaps ----------------
__global__ __launch_bounds__(256) void k1_lanes(const float* __restrict__ nf,
                                                u32* __restrict__ nodeinfo,
                                                u64* __restrict__ rowmask) {
    __shared__ u64 bm[LWORDS];
    int tid = threadIdx.x;
    int bid = blockIdx.x;
    if (tid < LWORDS) bm[tid] = 0;
    __syncthreads();
    int i = bid * 256 + tid;
    const float* b = nf + i * NPOS;
    u32 p = 0; int ln = 0;
#pragma unroll
    for (int k = 0; k < NPOS; ++k) {
        int bit = (int)b[k];                     // values are exactly 0.0 / 1.0
        if (bit) p |= (1u << k);
        if (k < NPOS - 1) ln = ln * 2 + bit;     // MSB-first, first 12 bits
    }
    bool valid = (b[0] >= 0.0f);
    int lv = valid ? ln : 0;
    nodeinfo[i] = ((u32)lv << 13) | p | (valid ? 0x80000000u : 0u);
    atomicOr(&bm[lv >> 6], 1ull << (lv & 63));
    __syncthreads();
    if (tid < LWORDS) rowmask[bid * LWORDS + tid] = bm[tid];
}

// ---------------- KA: sign-mask + bit-transpose, skipping unneeded rows ----------
__global__ __launch_bounds__(256) void kA_mask(const float* __restrict__ topo,
                                               const u64* __restrict__ rowmask,
                                               u64* __restrict__ T) {
    int bid = blockIdx.x;
    int tid = threadIdx.x;
    int tA = bid & 63;   // row tile
    int tB = bid >> 6;   // col tile
    __shared__ float tile[64 * 65];
    __shared__ u64 flags[2];

    if (tid < 2) {
        int sel = tid ? tB : tA;
        u64 m = 0;
#pragma unroll
        for (int b = 0; b < K1B; ++b) m |= rowmask[b * LWORDS + sel];
        flags[tid] = m;
    }
    __syncthreads();
    u64 rbits = flags[0], cbits = flags[1];

    const float* src = topo + (size_t)(tA * 64) * LL + tB * 64;
#pragma unroll
    for (int p = 0; p < 4; ++p) {
        int q = p * 1024 + tid * 4;
        int r = q >> 6, c = q & 63;
        if ((rbits >> r) & 1) {
            float4 v = *(const float4*)&src[(size_t)r * LL + c];
            float* d = &tile[r * 65 + c];
            d[0] = v.x; d[1] = v.y; d[2] = v.z; d[3] = v.w;
        }
    }
    __syncthreads();

    int w = tid >> 6, l = tid & 63;
#pragma unroll
    for (int cc = 0; cc < 16; ++cc) {
        int col = w * 16 + cc;
        if (!((cbits >> col) & 1)) continue;
        u64 m = __ballot(tile[l * 65 + col] >= 0.0f);
        if (l == 0) T[(size_t)(tB * 64 + col) * LWORDS + tA] = m;
    }
}

// ---------------- K3: column degree -> dinv[i] (ballot + popcount) ----------------
__global__ __launch_bounds__(256) void k3_deg(const u64* __restrict__ T,
                                              const u32* __restrict__ nodeinfo,
                                              float* __restrict__ dinv) {
    int i = blockIdx.x;
    __shared__ u64 row[LWORDS];
    __shared__ int red[4];
    int tid = threadIdx.x;
    u32 ni = nodeinfo[i];
    u32 li = (ni >> 13) & 0xFFFu;
    u32 vi = ni >> 31;
    if (tid < LWORDS) row[tid] = T[(size_t)li * LWORDS + tid];
    __syncthreads();
    int lane = tid & 63;
    int cnt = 0;
    for (int j = tid; j < N_NODES; j += 256) {
        u32 nj = nodeinfo[j];
        u32 lj = (nj >> 13) & 0xFFFu;
        u32 vj = nj >> 31;
        u32 bit = (u32)(row[lj >> 6] >> (lj & 63)) & 1u;
        u64 m = __ballot(vi & vj & bit);
        if (lane == 0) cnt += __popcll(m);
    }
    if (lane == 0) red[tid >> 6] = cnt;
    __syncthreads();
    if (tid == 0) {
        u32 selfbit = ((u32)(row[li >> 6] >> (li & 63)) & 1u) & vi;
        int d = red[0] + red[1] + red[2] + red[3] + (int)(1u - selfbit);
        dinv[i] = 1.0f / sqrtf((float)d);
    }
}

// ---------------- KP: build B-operand tables (hi/lo bf16, MFMA fragment layout) ------
// Slot for (j, f): chunk c=j>>5, grp=(j>>3)&3, e=j&7, lane=grp*16+f, idx=c*512+lane*8+e.
// z[j][f] = vj * dinv_j * xbit_f(j); z = hi + lo exactly to ~2^-16 rel.
__global__ __launch_bounds__(256) void kP_btab(const u32* __restrict__ nodeinfo,
                                               const float* __restrict__ dinv,
                                               unsigned short* __restrict__ Bhi,
                                               unsigned short* __restrict__ Blo,
                                               unsigned short* __restrict__ ljtab) {
    int j = blockIdx.x * 256 + threadIdx.x;
    u32 nj = nodeinfo[j];
    float dv = dinv[j];
    u32 vj = nj >> 31;
    ljtab[j] = (unsigned short)((nj >> 13) & 0xFFFu);
    int c = j >> 5, grp = (j >> 3) & 3, e = j & 7;
    int base = c * 512 + grp * 16 * 8 + e;
#pragma unroll
    for (int f = 0; f < NPOS; ++f) {
        float z = (vj & ((nj >> f) & 1u)) ? dv : 0.0f;
        unsigned short hi = (unsigned short)(__float_as_uint(z) >> 16);
        float lof = z - __uint_as_float((u32)hi << 16);
        unsigned short lo = (unsigned short)(__float_as_uint(lof) >> 16);
        Bhi[base + f * 8] = hi;
        Blo[base + f * 8] = lo;
    }
}

// ---------------- K4M: agg partials via MFMA -----------------------------------------
// aggp[s][i][f] = dinv_i * (vi ? sum_seg + self(s==0) : x_if(s==0))
// Wave = one 16-i tile; A[i][j] = T-bit(row_i, lane_j) as bf16 0/1; B from tables.
__global__ __launch_bounds__(256) void k4m(const u64* __restrict__ T,
                                           const unsigned short* __restrict__ ljtab,
                                           const unsigned short* __restrict__ Bhi,
                                           const unsigned short* __restrict__ Blo,
                                           const u32* __restrict__ nodeinfo,
                                           const float* __restrict__ dinv,
                                           float* __restrict__ aggp) {
    __shared__ u64 trows[64 * 65];          // 64 i-rows x 64 words, stride 65 (bank-safe)
    __shared__ unsigned short ljs[KS == 0 ? 1 : CPS * 32];   // 384 lanes of this segment
    int tid = threadIdx.x;
    int g = blockIdx.x;                     // 48 groups of 64 i
    int s = blockIdx.y;                     // segment
    int ibase = g * 64;

    for (int idx = tid; idx < 64 * 64; idx += 256) {
        int r = idx >> 6, w = idx & 63;
        u32 li = (nodeinfo[ibase + r] >> 13) & 0xFFFu;
        trows[r * 65 + w] = T[(size_t)li * LWORDS + w];
    }
    for (int idx = tid; idx < CPS * 32; idx += 256) ljs[idx] = ljtab[s * CPS * 32 + idx];
    __syncthreads();

    int wave = tid >> 6, l = tid & 63;
    int arow = wave * 16 + (l & 15);        // A-row (i-local) for this lane
    int grp = l >> 4;
    const u32* myrow32 = (const u32*)&trows[arow * 65];
    const u32* lj32 = (const u32*)ljs;

    f32x4 acch = {0.f, 0.f, 0.f, 0.f}, accl = {0.f, 0.f, 0.f, 0.f};
    for (int c = 0; c < CPS; ++c) {
        int jb = c * 32 + grp * 8;          // local j of element e=0
        u32 apk[4];
#pragma unroll
        for (int ee = 0; ee < 4; ++ee) {
            u32 pr = lj32[(jb >> 1) + ee];  // two u16 lanes
            u32 lj0 = pr & 0xFFFFu, lj1 = pr >> 16;
            u32 b0 = (myrow32[lj0 >> 5] >> (lj0 & 31)) & 1u;
            u32 b1 = (myrow32[lj1 >> 5] >> (lj1 & 31)) & 1u;
            apk[ee] = (b0 ? 0x3F80u : 0u) | (b1 ? 0x3F800000u : 0u);
        }
        union { u32 u[4]; bf16x8 v; } au;
        au.u[0] = apk[0]; au.u[1] = apk[1]; au.u[2] = apk[2]; au.u[3] = apk[3];
        int gc = s * CPS + c;
        bf16x8 bh = *(const bf16x8*)&Bhi[gc * 512 + l * 8];
        bf16x8 bl = *(const bf16x8*)&Blo[gc * 512 + l * 8];
        acch = __builtin_amdgcn_mfma_f32_16x16x32_bf16(au.v, bh, acch, 0, 0, 0);
        accl = __builtin_amdgcn_mfma_f32_16x16x32_bf16(au.v, bl, accl, 0, 0, 0);
    }

    int f = l & 15;
    if (f < NPOS) {
#pragma unroll
        for (int r = 0; r < 4; ++r) {
            int rloc = wave * 16 + grp * 4 + r;     // D row = (l>>4)*4 + reg
            int i = ibase + rloc;
            float sum = acch[r] + accl[r];
            u32 ni = nodeinfo[i];
            u32 vi = ni >> 31;
            float di = dinv[i];
            float xf = (float)((ni >> f) & 1u);
            u32 li = (ni >> 13) & 0xFFFu;
            float val;
            if (s == 0) {
                u32 sb = ((u32)(trows[rloc * 65 + (li >> 6)] >> (li & 63)) & 1u) & vi;
                val = vi ? (sum + (1.0f - (float)sb) * di * xf) : xf;
            } else {
                val = vi ? sum : 0.0f;
            }
            aggp[((size_t)s * N_NODES + i) * NPOS + f] = di * val;
        }
    }
}

// ---------------- K5: out[i][n] = bias[n] + sum_f (sum_s aggp[s][i][f]) * W[n][f] -----
#define NT 256
#define IT 32
__global__ __launch_bounds__(256) void k5_out(const float* __restrict__ aggp,
                                              const float* __restrict__ W,
                                              const float* __restrict__ bias,
                                              float* __restrict__ out) {
    __shared__ float Wt[NT * NPOS];
    __shared__ float bt[NT];
    __shared__ float at[IT * NPOS];
    int tid = threadIdx.x;
    int n0 = blockIdx.x * NT;
    int i0 = blockIdx.y * IT;
    const float4* Wsrc = (const float4*)&W[(size_t)n0 * NPOS];
    for (int idx = tid; idx < NT * NPOS / 4; idx += 256) ((float4*)Wt)[idx] = Wsrc[idx];
    if (tid < NT / 4) ((float4*)bt)[tid] = ((const float4*)&bias[n0])[tid];
    for (int idx = tid; idx < IT * NPOS; idx += 256) {
        float s = 0.0f;
#pragma unroll
        for (int sg = 0; sg < KS; ++sg)
            s += aggp[((size_t)sg * N_NODES + i0) * NPOS + idx];
        at[idx] = s;
    }
    __syncthreads();

    int n4 = (tid & 63) << 2;
    int r0 = (tid >> 6) << 3;

    float wr[NPOS][4];
#pragma unroll
    for (int fq = 0; fq < NPOS; ++fq)
#pragma unroll
        for (int r = 0; r < 4; ++r)
            wr[fq][r] = Wt[(n4 + r) * NPOS + fq];
    float b0 = bt[n4], b1 = bt[n4 + 1], b2 = bt[n4 + 2], b3 = bt[n4 + 3];

#pragma unroll
    for (int q = 0; q < 8; ++q) {
        int il = r0 + q;
        float a0 = b0, a1 = b1, a2 = b2, a3 = b3;
#pragma unroll
        for (int fq = 0; fq < NPOS; ++fq) {
            float av = at[il * NPOS + fq];
            a0 += av * wr[fq][0];
            a1 += av * wr[fq][1];
            a2 += av * wr[fq][2];
            a3 += av * wr[fq][3];
        }
        float4 o = make_float4(a0, a1, a2, a3);
        *(float4*)&out[(size_t)(i0 + il) * N_NODES + n0 + n4] = o;
    }
}

extern "C" void kernel_launch(void* const* d_in, const int* in_sizes, int n_in,
                              void* d_out, int out_size, void* d_ws, size_t ws_size,
                              hipStream_t stream) {
    const float* nf   = (const float*)d_in[0];   // node_feature [1,3072,13]
    const float* topo = (const float*)d_in[1];   // topo [1,1,4096,4096]
    const float* W    = (const float*)d_in[2];   // gcn_weight [3072,13]
    const float* bias = (const float*)d_in[3];   // gcn_bias [3072]
    float* out = (float*)d_out;

    // ws layout — every buffer fully overwritten by its producer; no memset anywhere
    char* ws = (char*)d_ws;
    u32*            nodeinfo = (u32*)ws;                         // 12 KB
    float*          dinv     = (float*)(ws + 12288);             // 12 KB
    u64*            rowmask  = (u64*)(ws + 24576);               // 6 KB
    unsigned short* ljtab    = (unsigned short*)(ws + 30720);    // 6 KB
    unsigned short* Bhi      = (unsigned short*)(ws + 36864);    // 96 KB
    unsigned short* Blo      = (unsigned short*)(ws + 135168);   // 96 KB
    float*          aggp     = (float*)(ws + 233472);            // 1248 KB (KS*3072*13*4)
    u64*            T        = (u64*)(ws + 1572864);             // 2 MB [4096][64]

    k1_lanes<<<K1B, 256, 0, stream>>>(nf, nodeinfo, rowmask);
    kA_mask<<<(LL / 64) * (LL / 64), 256, 0, stream>>>(topo, rowmask, T);
    k3_deg<<<N_NODES, 256, 0, stream>>>(T, nodeinfo, dinv);
    kP_btab<<<N_NODES / 256, 256, 0, stream>>>(nodeinfo, dinv, Bhi, Blo, ljtab);
    dim3 g4(N_NODES / 64, KS);
    k4m<<<g4, 256, 0, stream>>>(T, ljtab, Bhi, Blo, nodeinfo, dinv, aggp);
    dim3 g5(N_NODES / NT, N_NODES / IT);
    k5_out<<<g5, 256, 0, stream>>>(aggp, W, bias, out);
}